// Round 19
// baseline (66.578 us; speedup 1.0000x reference)
//
#include <hip/hip_runtime.h>
#include <hip/hip_bf16.h>
#include <math.h>

#define B_   8
#define C_   32
#define H_   256
#define W_   256
#define HW_  (H_*W_)
#define NPIX (B_*C_*H_*W_)   // offset of logdet in d_out

// LDS: 2 staged rows x 260 px-slots x 32ch bf16, p = w+1, halo zeros at p=0,257.
//   dword(r,p,cp) = r*4160 + p*16 + ((cp>>2) ^ ((p>>2)&3))*4 + (cp&3)
#define PW    260
#define ROWDW (PW*16)          // 4160 dwords per staged row
#define ROWB  (ROWDW*4)        // 16640 bytes

typedef __attribute__((ext_vector_type(8))) short short8;   // bf16x8 MFMA A/B frag
typedef __attribute__((ext_vector_type(4))) float f32x4;    // fp32x4 MFMA C/D frag
typedef __attribute__((ext_vector_type(2))) float f32x2;

static __device__ __forceinline__ short f2bf(float f) {
    union { __hip_bfloat16 h; short s; } u; u.h = __float2bfloat16(f); return u.s;
}
// pack two f32 -> bf16x2 dword (RNE), single HW instruction on gfx950
static __device__ __forceinline__ int cvtpk(float lo, float hi) {
    int r;
    asm("v_cvt_pk_bf16_f32 %0, %1, %2" : "=v"(r) : "v"(lo), "v"(hi));
    return r;
}

// ---------------------------------------------------------------------------
// Prep: weight-norm -> bf16 (RNE).
//   w1b[o*192 + tap*32 + c]                       (tap = kh*3+kw)
//   w2b[j*64 + slot]: hidden-dim permutation so conv2 B-frags are lane-local:
//     channel c (mt=c>>4, q=(c>>2)&3, reg=c&3) -> slot (mt>>1)*32+q*8+(mt&1)*4+reg
// ---------------------------------------------------------------------------
__global__ __launch_bounds__(64) void prep_kernel(
    const float* __restrict__ v1, const float* __restrict__ g1,
    const float* __restrict__ v2, const float* __restrict__ g2,
    short* __restrict__ w1b, short* __restrict__ w2b)
{
    const int t   = threadIdx.x;   // 0..63
    const int bid = blockIdx.x;    // 0..127
    if (bid < 64) {
        const int o = bid;
        float a0 = v1[o*192 + t];
        float a1 = v1[o*192 + t + 64];
        float a2 = v1[o*192 + t + 128];
        float s  = a0*a0 + a1*a1 + a2*a2;
        #pragma unroll
        for (int m = 32; m >= 1; m >>= 1) s += __shfl_xor(s, m, 64);
        const float inv = g1[o] / sqrtf(s);
        const int e0 = t, e1 = t + 64, e2 = t + 128;   // src idx = c*6 + tap
        w1b[o*192 + (e0%6)*32 + e0/6] = f2bf(a0*inv);
        w1b[o*192 + (e1%6)*32 + e1/6] = f2bf(a1*inv);
        w1b[o*192 + (e2%6)*32 + e2/6] = f2bf(a2*inv);
    } else {
        const int j = bid - 64;
        float a = v2[j*64 + t];
        float s = a*a;
        #pragma unroll
        for (int m = 32; m >= 1; m >>= 1) s += __shfl_xor(s, m, 64);
        const float inv = g2[j] / sqrtf(s);
        const int mt = t >> 4, r = t & 15;
        const int slot = (mt >> 1)*32 + ((r >> 2) << 3) + ((mt & 1) << 2) + (r & 3);
        w2b[j*64 + slot] = f2bf(a*inv);
    }
}

// ---------------------------------------------------------------------------
// Fused MFMA kernel: one block per (b,h); 4 waves, 64 px each; 2048 blocks.
// r18 with a LIVENESS-ONLY restructure targeting the unified register file:
// residency law (fits r7/r10/r9/r15/r18): waves/SIMD ~= 0.72*floor(512/
// (archVGPR + AGPR)). r18 = 108+64 = 172 -> cap 2. Target <= 104+64 = 168
// -> cap 3. Changes (zero extra work):
//   (1) voff/x-prefetch moved AFTER conv1 (was live across it);
//   (2) up0/up1 arrays eliminated: ELU+pack fused per-nt into conv2+epilogue
//       (8 transient pack regs instead of 32; AGPR peak stays 64);
//   (3) per-nt x slice loaded at iteration top (no 8-reg double buffer).
// conv1: D1[o][px] (A = weights, B = x-patch) -> lane holds o=4q+reg, px=lrow.
// conv2: lane-local B-frags (hidden dim pre-permuted in w2b).
// logdet: per-wave partial -> plain store (r7: no atomics).
// ---------------------------------------------------------------------------
__global__ __launch_bounds__(256) void flow_kernel(
    const float* __restrict__ x,
    const short* __restrict__ w1b, const short* __restrict__ w2b,
    const float* __restrict__ b1,  const float* __restrict__ b2,
    float* __restrict__ out, float* __restrict__ ldpart)
{
    __shared__ int ldsI[2*ROWDW];   // 33280 B

    const int bi0 = blockIdx.x;            // 0..2047
    const int bi  = (bi0 & 7) * 256 + (bi0 >> 3);   // XCD k owns image k
    const int b   = bi >> 8;
    const int h   = bi & 255;

    const int tid  = threadIdx.x;
    const int l    = tid & 63;
    const int wv   = tid >> 6;
    const int lrow = l & 15;
    const int q    = l >> 4;

    const float* xb = x + (size_t)b * (C_*HW_);
    float* ob       = out + (size_t)b * (C_*HW_);

    // ---- stage rows h-2 (r=0), h-1 (r=1): b128 writes only (r9 verbatim) ---
    {
        const int r   = tid >> 7;          // staged row index
        const int hr  = h - 2 + r;
        const int u   = tid & 127;
        const int w0  = u << 1;            // pixel pair w0, w0+1
        const int p0  = w0 + 1, p1 = w0 + 2;
        const int sw0 = (p0 >> 2) & 3, sw1 = (p1 >> 2) & 3;
        if (hr >= 0) {
            const float* pr = xb + (size_t)hr * W_ + w0;
            #pragma unroll
            for (int g = 0; g < 4; ++g) {          // channel octet 8g..8g+7
                f32x2 a[8];
                #pragma unroll
                for (int j = 0; j < 8; ++j)
                    a[j] = *(const f32x2*)(pr + (size_t)(8*g + j) * HW_);
                int4 d0, d1;
                d0.x = cvtpk(a[0][0], a[1][0]); d0.y = cvtpk(a[2][0], a[3][0]);
                d0.z = cvtpk(a[4][0], a[5][0]); d0.w = cvtpk(a[6][0], a[7][0]);
                d1.x = cvtpk(a[0][1], a[1][1]); d1.y = cvtpk(a[2][1], a[3][1]);
                d1.z = cvtpk(a[4][1], a[5][1]); d1.w = cvtpk(a[6][1], a[7][1]);
                *(int4*)&ldsI[r*ROWDW + p0*16 + ((g ^ sw0) << 2)] = d0;
                *(int4*)&ldsI[r*ROWDW + p1*16 + ((g ^ sw1) << 2)] = d1;
            }
        } else {
            const int4 z4 = {0,0,0,0};
            #pragma unroll
            for (int g = 0; g < 4; ++g) {
                *(int4*)&ldsI[r*ROWDW + p0*16 + ((g ^ sw0) << 2)] = z4;
                *(int4*)&ldsI[r*ROWDW + p1*16 + ((g ^ sw1) << 2)] = z4;
            }
        }
        // halo columns p=0 and p=257
        if (tid < 16) {
            const int rz = tid >> 3;
            const int pz = ((tid >> 2) & 1) ? 257 : 0;
            *(int4*)&ldsI[rz*ROWDW + pz*16 + ((tid & 3) << 2)] = (int4){0,0,0,0};
        }
    }
    __syncthreads();

    // ---- conv1: D1[o][px], bias pre-loaded into acc (r15 verbatim) ----------
    f32x4 acc1[4][4];
    #pragma unroll
    for (int mt = 0; mt < 4; ++mt) {
        const f32x4 bv = *(const f32x4*)(b1 + mt*16 + 4*q);
        #pragma unroll
        for (int nt = 0; nt < 4; ++nt) acc1[mt][nt] = bv;
    }

    #pragma unroll
    for (int tap = 0; tap < 6; ++tap) {
        const int rb = (tap < 3) ? 0 : ROWB;
        const int dw = (tap % 3) - 1;
        short8 wf[4];
        #pragma unroll
        for (int mt = 0; mt < 4; ++mt)
            wf[mt] = *(const short8*)(w1b + (mt*16 + lrow)*192 + tap*32 + q*8);
        #pragma unroll
        for (int nt = 0; nt < 4; ++nt) {
            const int p = wv*64 + nt*16 + lrow + dw + 1;    // halo-shifted
            const int byteoff = rb + p*64 + ((q ^ ((p >> 2) & 3)) << 4);
            const short8 xf = *(const short8*)((const char*)ldsI + byteoff);
            #pragma unroll
            for (int mt = 0; mt < 4; ++mt)
                acc1[mt][nt] = __builtin_amdgcn_mfma_f32_16x16x32_bf16(
                                   wf[mt], xf, acc1[mt][nt], 0, 0, 0);
        }
    }

    // ---- voffsets (shared by epilogue loads AND stores), computed late -----
    const int cb0 = h*W_ + wv*64 + lrow;
    int voff[8];                           // 32-bit element offsets
    #pragma unroll
    for (int jj = 0; jj < 8; ++jj)
        voff[jj] = ((jj >> 2)*16 + 4*q + (jj & 3)) * HW_ + cb0;

    // ---- conv2 weights + biases (b2s has +2 pre-folded) ---------------------
    short8 a2f[2][4];
    #pragma unroll
    for (int kt = 0; kt < 2; ++kt)
        #pragma unroll
        for (int mt2 = 0; mt2 < 4; ++mt2)
            a2f[kt][mt2] = *(const short8*)(w2b + (mt2*16 + lrow)*64 + kt*32 + q*8);

    f32x4 b2m[2], b2s[2];
    #pragma unroll
    for (int mt2 = 0; mt2 < 2; ++mt2) {
        b2m[mt2] = *(const f32x4*)(b2 + mt2*16 + 4*q);
        b2s[mt2] = *(const f32x4*)(b2 + 32 + mt2*16 + 4*q)
                 + (f32x4){2.f, 2.f, 2.f, 2.f};
    }

    // ---- fused per-nt: x-slice load -> ELU+pack -> conv2 -> epilogue --------
    float ldsum = 0.f;
    #pragma unroll
    for (int nt = 0; nt < 4; ++nt) {
        // x slice for this nt: issued early in the iteration, used at the end
        float xc[8];
        #pragma unroll
        for (int jj = 0; jj < 8; ++jj)
            xc[jj] = xb[(unsigned)voff[jj] + nt*16];

        // ELU + pack this nt's acc1 slice (transient 8 regs; acc1 slice dies)
        float e[16];
        #pragma unroll
        for (int mt = 0; mt < 4; ++mt)
            #pragma unroll
            for (int rg = 0; rg < 4; ++rg) {
                const float v = acc1[mt][nt][rg];
                e[mt*4 + rg] = v > 0.f ? v : (__expf(v) - 1.f);
            }
        union { int4 i; short8 s; } u0, u1;
        u0.i.x = cvtpk(e[0],  e[1]);  u0.i.y = cvtpk(e[2],  e[3]);
        u0.i.z = cvtpk(e[4],  e[5]);  u0.i.w = cvtpk(e[6],  e[7]);
        u1.i.x = cvtpk(e[8],  e[9]);  u1.i.y = cvtpk(e[10], e[11]);
        u1.i.z = cvtpk(e[12], e[13]); u1.i.w = cvtpk(e[14], e[15]);

        // conv2 (acc2 transient; AGPR peak stays 64: acc1 slice freed above)
        f32x4 acc2[4];
        #pragma unroll
        for (int mt2 = 0; mt2 < 4; ++mt2) {
            f32x4 t0 = __builtin_amdgcn_mfma_f32_16x16x32_bf16(
                           a2f[0][mt2], u0.s, (f32x4){0.f,0.f,0.f,0.f}, 0, 0, 0);
            acc2[mt2] = __builtin_amdgcn_mfma_f32_16x16x32_bf16(
                           a2f[1][mt2], u1.s, t0, 0, 0, 0);
        }

        // epilogue: sigmoid/affine/logdet
        float pr8 = 1.f;                      // product of 8 scales -> one log
        #pragma unroll
        for (int mt2 = 0; mt2 < 2; ++mt2)
            #pragma unroll
            for (int rg = 0; rg < 4; ++rg) {
                const int jj = mt2*4 + rg;
                const float mu = acc2[mt2][rg]     + b2m[mt2][rg];
                const float z  = acc2[mt2 + 2][rg] + b2s[mt2][rg];   // +2 folded
                const float sc = 1.f / (1.f + __expf(-z));
                pr8 *= sc;
                ob[(unsigned)voff[jj] + nt*16] = xc[jj] * sc + mu;
            }
        ldsum += __logf(pr8);
    }

    // ---- logdet partial: plain store, no atomic ----------------------------
    #pragma unroll
    for (int m = 32; m >= 1; m >>= 1) ldsum += __shfl_xor(ldsum, m, 64);
    if (l == 0) ldpart[(size_t)bi * 4 + wv] = ldsum;   // bi = b*256 + h
}

// ---------------------------------------------------------------------------
// Final reduce: 8 blocks, each sums 1024 partials -> logdet[b].
// ---------------------------------------------------------------------------
__global__ __launch_bounds__(256) void reduce_kernel(
    const float* __restrict__ ldpart, float* __restrict__ logdet)
{
    __shared__ float r4[4];
    const int b = blockIdx.x;
    const int t = threadIdx.x;
    const f32x4 v = *(const f32x4*)(ldpart + (size_t)b*1024 + t*4);
    float s = v[0] + v[1] + v[2] + v[3];
    #pragma unroll
    for (int m = 32; m >= 1; m >>= 1) s += __shfl_xor(s, m, 64);
    if ((t & 63) == 0) r4[t >> 6] = s;
    __syncthreads();
    if (t == 0) logdet[b] = r4[0] + r4[1] + r4[2] + r4[3];
}

// ---------------------------------------------------------------------------
extern "C" void kernel_launch(void* const* d_in, const int* in_sizes, int n_in,
                              void* d_out, int out_size, void* d_ws, size_t ws_size,
                              hipStream_t stream)
{
    const float* x  = (const float*)d_in[0];
    const float* v1 = (const float*)d_in[1];
    const float* g1 = (const float*)d_in[2];
    const float* b1 = (const float*)d_in[3];
    const float* v2 = (const float*)d_in[4];
    const float* g2 = (const float*)d_in[5];
    const float* b2 = (const float*)d_in[6];

    float* out    = (float*)d_out;
    float* logdet = out + NPIX;

    short* w1b    = (short*)d_ws;                    // 24576 B
    short* w2b    = w1b + 12288;                     //  8192 B
    float* ldpart = (float*)((char*)d_ws + 32768);   //  8192 f32 partials

    prep_kernel<<<128, 64, 0, stream>>>(v1, g1, v2, g2, w1b, w2b);
    flow_kernel<<<B_ * H_, 256, 0, stream>>>(x, w1b, w2b, b1, b2, out, ldpart);
    reduce_kernel<<<B_, 256, 0, stream>>>(ldpart, logdet);
}

// Round 20
// 62.603 us; speedup vs baseline: 1.0635x; 1.0635x over previous
//
#include <hip/hip_runtime.h>
#include <hip/hip_bf16.h>
#include <math.h>

#define B_   8
#define C_   32
#define H_   256
#define W_   256
#define HW_  (H_*W_)
#define NPIX (B_*C_*H_*W_)   // offset of logdet in d_out

// LDS: 2 staged rows x 260 px-slots x 32ch bf16, p = w+1, halo zeros at p=0,257.
//   dword(r,p,cp) = r*4160 + p*16 + ((cp>>2) ^ ((p>>2)&3))*4 + (cp&3)
#define PW    260
#define ROWDW (PW*16)          // 4160 dwords per staged row
#define ROWB  (ROWDW*4)        // 16640 bytes

typedef __attribute__((ext_vector_type(8))) short short8;   // bf16x8 MFMA A/B frag
typedef __attribute__((ext_vector_type(4))) float f32x4;    // fp32x4 MFMA C/D frag
typedef __attribute__((ext_vector_type(2))) float f32x2;

static __device__ __forceinline__ short f2bf(float f) {
    union { __hip_bfloat16 h; short s; } u; u.h = __float2bfloat16(f); return u.s;
}
// pack two f32 -> bf16x2 dword (RNE), single HW instruction on gfx950
static __device__ __forceinline__ int cvtpk(float lo, float hi) {
    int r;
    asm("v_cvt_pk_bf16_f32 %0, %1, %2" : "=v"(r) : "v"(lo), "v"(hi));
    return r;
}

// ---------------------------------------------------------------------------
// Prep: weight-norm -> bf16 (RNE).
//   w1b[o*192 + tap*32 + c]                       (tap = kh*3+kw)
//   w2b[j*64 + slot]: hidden-dim permutation so conv2 B-frags are lane-local:
//     channel c (mt=c>>4, q=(c>>2)&3, reg=c&3) -> slot (mt>>1)*32+q*8+(mt&1)*4+reg
// ---------------------------------------------------------------------------
__global__ __launch_bounds__(64) void prep_kernel(
    const float* __restrict__ v1, const float* __restrict__ g1,
    const float* __restrict__ v2, const float* __restrict__ g2,
    short* __restrict__ w1b, short* __restrict__ w2b)
{
    const int t   = threadIdx.x;   // 0..63
    const int bid = blockIdx.x;    // 0..127
    if (bid < 64) {
        const int o = bid;
        float a0 = v1[o*192 + t];
        float a1 = v1[o*192 + t + 64];
        float a2 = v1[o*192 + t + 128];
        float s  = a0*a0 + a1*a1 + a2*a2;
        #pragma unroll
        for (int m = 32; m >= 1; m >>= 1) s += __shfl_xor(s, m, 64);
        const float inv = g1[o] / sqrtf(s);
        const int e0 = t, e1 = t + 64, e2 = t + 128;   // src idx = c*6 + tap
        w1b[o*192 + (e0%6)*32 + e0/6] = f2bf(a0*inv);
        w1b[o*192 + (e1%6)*32 + e1/6] = f2bf(a1*inv);
        w1b[o*192 + (e2%6)*32 + e2/6] = f2bf(a2*inv);
    } else {
        const int j = bid - 64;
        float a = v2[j*64 + t];
        float s = a*a;
        #pragma unroll
        for (int m = 32; m >= 1; m >>= 1) s += __shfl_xor(s, m, 64);
        const float inv = g2[j] / sqrtf(s);
        const int mt = t >> 4, r = t & 15;
        const int slot = (mt >> 1)*32 + ((r >> 2) << 3) + ((mt & 1) << 2) + (r & 3);
        w2b[j*64 + slot] = f2bf(a*inv);
    }
}

// ---------------------------------------------------------------------------
// Fused MFMA kernel: one block per (b,h); 4 waves, 64 px each; 2048 blocks.
// Session champion (r18, 62.65us). Structure: stage rows h-2,h-1 (halo'd,
// b128-only LDS writes, cvtpk packing) -> bar -> conv1 via MFMA (A=weights,
// B=x-patch; lane holds o=4q+reg, px=lrow) -> ELU+pack in-register -> conv2
// via MFMA (lane-local B-frags, hidden dim pre-permuted in w2b) -> fused
// per-nt epilogue (shared 32-bit voffsets for x loads AND out stores; x slice
// double-buffered one iteration ahead; +2 folded into b2s; one __logf per 8
// scales) -> per-wave logdet partial, plain store (no atomics).
// ---------------------------------------------------------------------------
__global__ __launch_bounds__(256) void flow_kernel(
    const float* __restrict__ x,
    const short* __restrict__ w1b, const short* __restrict__ w2b,
    const float* __restrict__ b1,  const float* __restrict__ b2,
    float* __restrict__ out, float* __restrict__ ldpart)
{
    __shared__ int ldsI[2*ROWDW];   // 33280 B

    const int bi0 = blockIdx.x;            // 0..2047
    const int bi  = (bi0 & 7) * 256 + (bi0 >> 3);   // XCD k owns image k
    const int b   = bi >> 8;
    const int h   = bi & 255;

    const int tid  = threadIdx.x;
    const int l    = tid & 63;
    const int wv   = tid >> 6;
    const int lrow = l & 15;
    const int q    = l >> 4;

    const float* xb = x + (size_t)b * (C_*HW_);
    float* ob       = out + (size_t)b * (C_*HW_);

    // ---- stage rows h-2 (r=0), h-1 (r=1): b128 writes only -----------------
    {
        const int r   = tid >> 7;          // staged row index
        const int hr  = h - 2 + r;
        const int u   = tid & 127;
        const int w0  = u << 1;            // pixel pair w0, w0+1
        const int p0  = w0 + 1, p1 = w0 + 2;
        const int sw0 = (p0 >> 2) & 3, sw1 = (p1 >> 2) & 3;
        if (hr >= 0) {
            const float* pr = xb + (size_t)hr * W_ + w0;
            #pragma unroll
            for (int g = 0; g < 4; ++g) {          // channel octet 8g..8g+7
                f32x2 a[8];
                #pragma unroll
                for (int j = 0; j < 8; ++j)
                    a[j] = *(const f32x2*)(pr + (size_t)(8*g + j) * HW_);
                int4 d0, d1;
                d0.x = cvtpk(a[0][0], a[1][0]); d0.y = cvtpk(a[2][0], a[3][0]);
                d0.z = cvtpk(a[4][0], a[5][0]); d0.w = cvtpk(a[6][0], a[7][0]);
                d1.x = cvtpk(a[0][1], a[1][1]); d1.y = cvtpk(a[2][1], a[3][1]);
                d1.z = cvtpk(a[4][1], a[5][1]); d1.w = cvtpk(a[6][1], a[7][1]);
                *(int4*)&ldsI[r*ROWDW + p0*16 + ((g ^ sw0) << 2)] = d0;
                *(int4*)&ldsI[r*ROWDW + p1*16 + ((g ^ sw1) << 2)] = d1;
            }
        } else {
            const int4 z4 = {0,0,0,0};
            #pragma unroll
            for (int g = 0; g < 4; ++g) {
                *(int4*)&ldsI[r*ROWDW + p0*16 + ((g ^ sw0) << 2)] = z4;
                *(int4*)&ldsI[r*ROWDW + p1*16 + ((g ^ sw1) << 2)] = z4;
            }
        }
        // halo columns p=0 and p=257
        if (tid < 16) {
            const int rz = tid >> 3;
            const int pz = ((tid >> 2) & 1) ? 257 : 0;
            *(int4*)&ldsI[rz*ROWDW + pz*16 + ((tid & 3) << 2)] = (int4){0,0,0,0};
        }
    }
    __syncthreads();

    // ---- shared voffsets for epilogue loads AND stores; nt=0 slice hoisted -
    const int cb0 = h*W_ + wv*64 + lrow;
    int voff[8];                           // 32-bit element offsets (x < 16M elems)
    #pragma unroll
    for (int jj = 0; jj < 8; ++jj)
        voff[jj] = ((jj >> 2)*16 + 4*q + (jj & 3)) * HW_ + cb0;

    float xcur[8], xnxt[8];
    #pragma unroll
    for (int jj = 0; jj < 8; ++jj)
        xcur[jj] = xb[(unsigned)voff[jj]];           // nt=0, hides under conv1

    // ---- conv1: D1[o][px], bias pre-loaded into acc -------------------------
    f32x4 acc1[4][4];
    #pragma unroll
    for (int mt = 0; mt < 4; ++mt) {
        const f32x4 bv = *(const f32x4*)(b1 + mt*16 + 4*q);
        #pragma unroll
        for (int nt = 0; nt < 4; ++nt) acc1[mt][nt] = bv;
    }

    #pragma unroll
    for (int tap = 0; tap < 6; ++tap) {
        const int rb = (tap < 3) ? 0 : ROWB;
        const int dw = (tap % 3) - 1;
        short8 wf[4];
        #pragma unroll
        for (int mt = 0; mt < 4; ++mt)
            wf[mt] = *(const short8*)(w1b + (mt*16 + lrow)*192 + tap*32 + q*8);
        #pragma unroll
        for (int nt = 0; nt < 4; ++nt) {
            const int p = wv*64 + nt*16 + lrow + dw + 1;    // halo-shifted
            const int byteoff = rb + p*64 + ((q ^ ((p >> 2) & 3)) << 4);
            const short8 xf = *(const short8*)((const char*)ldsI + byteoff);
            #pragma unroll
            for (int mt = 0; mt < 4; ++mt)
                acc1[mt][nt] = __builtin_amdgcn_mfma_f32_16x16x32_bf16(
                                   wf[mt], xf, acc1[mt][nt], 0, 0, 0);
        }
    }

    // ---- ELU + pack ALL nt: acc1 (64 f32) dies into 32 bf16 regs ------------
    int4 up0[4], up1[4];
    #pragma unroll
    for (int nt = 0; nt < 4; ++nt) {
        float e[16];
        #pragma unroll
        for (int mt = 0; mt < 4; ++mt)
            #pragma unroll
            for (int rg = 0; rg < 4; ++rg) {
                const float v = acc1[mt][nt][rg];
                e[mt*4 + rg] = v > 0.f ? v : (__expf(v) - 1.f);
            }
        up0[nt].x = cvtpk(e[0],  e[1]);  up0[nt].y = cvtpk(e[2],  e[3]);
        up0[nt].z = cvtpk(e[4],  e[5]);  up0[nt].w = cvtpk(e[6],  e[7]);
        up1[nt].x = cvtpk(e[8],  e[9]);  up1[nt].y = cvtpk(e[10], e[11]);
        up1[nt].z = cvtpk(e[12], e[13]); up1[nt].w = cvtpk(e[14], e[15]);
    }

    // ---- conv2 weights + biases (b2s has +2 pre-folded) ----------------------
    short8 a2f[2][4];
    #pragma unroll
    for (int kt = 0; kt < 2; ++kt)
        #pragma unroll
        for (int mt2 = 0; mt2 < 4; ++mt2)
            a2f[kt][mt2] = *(const short8*)(w2b + (mt2*16 + lrow)*64 + kt*32 + q*8);

    f32x4 b2m[2], b2s[2];
    #pragma unroll
    for (int mt2 = 0; mt2 < 2; ++mt2) {
        b2m[mt2] = *(const f32x4*)(b2 + mt2*16 + 4*q);
        b2s[mt2] = *(const f32x4*)(b2 + 32 + mt2*16 + 4*q)
                 + (f32x4){2.f, 2.f, 2.f, 2.f};
    }

    // ---- conv2 + epilogue fused per-nt; next-nt x slice prefetched -----------
    float ldsum = 0.f;
    #pragma unroll
    for (int nt = 0; nt < 4; ++nt) {
        if (nt < 3) {
            #pragma unroll
            for (int jj = 0; jj < 8; ++jj)
                xnxt[jj] = xb[(unsigned)voff[jj] + (nt + 1)*16];
        }

        union { int4 i; short8 s; } u0, u1;
        u0.i = up0[nt];
        u1.i = up1[nt];

        f32x4 acc2[4];
        #pragma unroll
        for (int mt2 = 0; mt2 < 4; ++mt2) {
            f32x4 t0 = __builtin_amdgcn_mfma_f32_16x16x32_bf16(
                           a2f[0][mt2], u0.s, (f32x4){0.f,0.f,0.f,0.f}, 0, 0, 0);
            acc2[mt2] = __builtin_amdgcn_mfma_f32_16x16x32_bf16(
                           a2f[1][mt2], u1.s, t0, 0, 0, 0);
        }

        float pr8 = 1.f;                      // product of 8 scales -> one log
        #pragma unroll
        for (int mt2 = 0; mt2 < 2; ++mt2)
            #pragma unroll
            for (int rg = 0; rg < 4; ++rg) {
                const int jj = mt2*4 + rg;
                const float mu = acc2[mt2][rg]     + b2m[mt2][rg];
                const float z  = acc2[mt2 + 2][rg] + b2s[mt2][rg];   // +2 folded
                const float sc = 1.f / (1.f + __expf(-z));
                pr8 *= sc;
                ob[(unsigned)voff[jj] + nt*16] = xcur[jj] * sc + mu;
            }
        ldsum += __logf(pr8);

        if (nt < 3) {
            #pragma unroll
            for (int jj = 0; jj < 8; ++jj) xcur[jj] = xnxt[jj];   // SSA renames
        }
    }

    // ---- logdet partial: plain store, no atomic ----------------------------
    #pragma unroll
    for (int m = 32; m >= 1; m >>= 1) ldsum += __shfl_xor(ldsum, m, 64);
    if (l == 0) ldpart[(size_t)bi * 4 + wv] = ldsum;   // bi = b*256 + h
}

// ---------------------------------------------------------------------------
// Final reduce: 8 blocks, each sums 1024 partials -> logdet[b].
// ---------------------------------------------------------------------------
__global__ __launch_bounds__(256) void reduce_kernel(
    const float* __restrict__ ldpart, float* __restrict__ logdet)
{
    __shared__ float r4[4];
    const int b = blockIdx.x;
    const int t = threadIdx.x;
    const f32x4 v = *(const f32x4*)(ldpart + (size_t)b*1024 + t*4);
    float s = v[0] + v[1] + v[2] + v[3];
    #pragma unroll
    for (int m = 32; m >= 1; m >>= 1) s += __shfl_xor(s, m, 64);
    if ((t & 63) == 0) r4[t >> 6] = s;
    __syncthreads();
    if (t == 0) logdet[b] = r4[0] + r4[1] + r4[2] + r4[3];
}

// ---------------------------------------------------------------------------
extern "C" void kernel_launch(void* const* d_in, const int* in_sizes, int n_in,
                              void* d_out, int out_size, void* d_ws, size_t ws_size,
                              hipStream_t stream)
{
    const float* x  = (const float*)d_in[0];
    const float* v1 = (const float*)d_in[1];
    const float* g1 = (const float*)d_in[2];
    const float* b1 = (const float*)d_in[3];
    const float* v2 = (const float*)d_in[4];
    const float* g2 = (const float*)d_in[5];
    const float* b2 = (const float*)d_in[6];

    float* out    = (float*)d_out;
    float* logdet = out + NPIX;

    short* w1b    = (short*)d_ws;                    // 24576 B
    short* w2b    = w1b + 12288;                     //  8192 B
    float* ldpart = (float*)((char*)d_ws + 32768);   //  8192 f32 partials

    prep_kernel<<<128, 64, 0, stream>>>(v1, g1, v2, g2, w1b, w2b);
    flow_kernel<<<B_ * H_, 256, 0, stream>>>(x, w1b, w2b, b1, b2, out, ldpart);
    reduce_kernel<<<B_, 256, 0, stream>>>(ldpart, logdet);
}